// Round 2
// baseline (290.561 us; speedup 1.0000x reference)
//
#include <hip/hip_runtime.h>

typedef _Float16 half8 __attribute__((ext_vector_type(8)));
typedef _Float16 half4_t __attribute__((ext_vector_type(4)));
typedef float f32x4 __attribute__((ext_vector_type(4)));

#define MFMA(a, b, c) __builtin_amdgcn_mfma_f32_16x16x32_f16(a, b, c, 0, 0, 0)

constexpr int T_TOK = 4096;
constexpr int DMODEL = 1024;
constexpr int WLOC = 256;

// ---------- cast f32 -> f16 (8 elems/thread, exact grid) ----------
__global__ __launch_bounds__(256) void k_cast(const float* __restrict__ in,
                                              _Float16* __restrict__ out) {
  int i = (blockIdx.x * 256 + threadIdx.x) * 8;
  f32x4 a = *(const f32x4*)(in + i);
  f32x4 b = *(const f32x4*)(in + i + 4);
  half8 h;
  h[0] = (_Float16)a[0]; h[1] = (_Float16)a[1]; h[2] = (_Float16)a[2]; h[3] = (_Float16)a[3];
  h[4] = (_Float16)b[0]; h[5] = (_Float16)b[1]; h[6] = (_Float16)b[2]; h[7] = (_Float16)b[3];
  *(half8*)(out + i) = h;
}

// ---------- transpose + cast: in f32 [R][C] -> out f16 [C][R] ----------
__global__ __launch_bounds__(256) void k_transpose_cast(const float* __restrict__ in,
                                                        _Float16* __restrict__ out,
                                                        int R, int C) {
  __shared__ float tile[64][65];
  int r0 = blockIdx.y * 64, c0 = blockIdx.x * 64;
  int tr = threadIdx.x >> 4;         // 0..15
  int tc = (threadIdx.x & 15) * 4;   // 0..60
#pragma unroll
  for (int p = 0; p < 4; ++p) {
    int r = p * 16 + tr;
    f32x4 v = *(const f32x4*)&in[(size_t)(r0 + r) * C + c0 + tc];
    tile[r][tc + 0] = v[0]; tile[r][tc + 1] = v[1];
    tile[r][tc + 2] = v[2]; tile[r][tc + 3] = v[3];
  }
  __syncthreads();
#pragma unroll
  for (int p = 0; p < 4; ++p) {
    int c = p * 16 + tr;
    half4_t h;
    h[0] = (_Float16)tile[tc + 0][c];
    h[1] = (_Float16)tile[tc + 1][c];
    h[2] = (_Float16)tile[tc + 2][c];
    h[3] = (_Float16)tile[tc + 3][c];
    *(half4_t*)&out[(size_t)(c0 + c) * R + r0 + tc] = h;
  }
}

// ---------- gate: sigmoid(hidden @ Wg + bg), one wave per token ----------
__global__ __launch_bounds__(256) void k_gate(const float* __restrict__ hs,
                                              const float* __restrict__ Wg,
                                              const float* __restrict__ bg,
                                              float* __restrict__ gate) {
  int t = blockIdx.x * 4 + (threadIdx.x >> 6);
  int lane = threadIdx.x & 63;
  float s = 0.f;
#pragma unroll
  for (int i = 0; i < 16; ++i)
    s += hs[(size_t)t * DMODEL + lane + i * 64] * Wg[lane + i * 64];
#pragma unroll
  for (int off = 32; off; off >>= 1) s += __shfl_xor(s, off);
  if (lane == 0) gate[t] = 1.f / (1.f + __expf(-(s + bg[0])));
}

// ---------- f16 MFMA GEMM: C = A[M][K] * Bt[N][K]^T + bias ----------
// MODE 0: epilogue splits qkv into q[h][t][d], k[h][t][d], vT[h][d][t] (f16)
// MODE 1: plain fp32 output
template <int MODE>
__global__ __launch_bounds__(256) void k_gemm(const _Float16* __restrict__ A,
                                              const _Float16* __restrict__ Bt,
                                              const float* __restrict__ bias,
                                              float* __restrict__ Cout,
                                              _Float16* __restrict__ qh,
                                              _Float16* __restrict__ kh,
                                              _Float16* __restrict__ vt,
                                              int M, int N, int K) {
  __shared__ _Float16 As[128][40];
  __shared__ _Float16 Bs[128][40];
  int tid = threadIdx.x;
  int lane = tid & 63, wave = tid >> 6;
  int wm = wave >> 1, wn = wave & 1;
  int m0 = blockIdx.y * 128, n0 = blockIdx.x * 128;
  int lr = lane & 15, lk = (lane >> 4) * 8;
  int sr = tid >> 2, sc = (tid & 3) * 8;
  f32x4 acc[4][4] = {};

  for (int kt = 0; kt < K; kt += 32) {
    __syncthreads();
    *(half8*)&As[sr][sc]      = *(const half8*)&A[(size_t)(m0 + sr) * K + kt + sc];
    *(half8*)&As[sr + 64][sc] = *(const half8*)&A[(size_t)(m0 + sr + 64) * K + kt + sc];
    *(half8*)&Bs[sr][sc]      = *(const half8*)&Bt[(size_t)(n0 + sr) * K + kt + sc];
    *(half8*)&Bs[sr + 64][sc] = *(const half8*)&Bt[(size_t)(n0 + sr + 64) * K + kt + sc];
    __syncthreads();
    half8 af[4], bf[4];
#pragma unroll
    for (int i = 0; i < 4; ++i) af[i] = *(half8*)&As[wm * 64 + i * 16 + lr][lk];
#pragma unroll
    for (int i = 0; i < 4; ++i) bf[i] = *(half8*)&Bs[wn * 64 + i * 16 + lr][lk];
#pragma unroll
    for (int i = 0; i < 4; ++i)
#pragma unroll
      for (int j = 0; j < 4; ++j)
        acc[i][j] = MFMA(af[i], bf[j], acc[i][j]);
  }

  int lg2 = lane >> 4;
#pragma unroll
  for (int j = 0; j < 4; ++j) {
    int n = n0 + wn * 64 + j * 16 + lr;
    float b = bias[n];
#pragma unroll
    for (int i = 0; i < 4; ++i) {
#pragma unroll
      for (int r = 0; r < 4; ++r) {
        int m = m0 + wm * 64 + i * 16 + lg2 * 4 + r;
        float v = acc[i][j][r] + b;
        if (MODE == 1) {
          Cout[(size_t)m * N + n] = v;
        } else {
          int hh = (n >> 6) & 15, d = n & 63;
          if (n < 1024)      qh[((size_t)hh * T_TOK + m) * 64 + d] = (_Float16)v;
          else if (n < 2048) kh[((size_t)hh * T_TOK + m) * 64 + d] = (_Float16)v;
          else               vt[((size_t)hh * 64 + d) * T_TOK + m] = (_Float16)v;
        }
      }
    }
  }
}

// ---------- fused local+global attention + gate combine ----------
// 1 wave per (head, 16-query block). Online softmax in fp32, -1e30 sentinel.
__global__ __launch_bounds__(64) void k_attn(const _Float16* __restrict__ q_all,
                                             const _Float16* __restrict__ k_all,
                                             const _Float16* __restrict__ vT_all,
                                             const float* __restrict__ gate,
                                             _Float16* __restrict__ attn_h) {
  __shared__ __align__(16) _Float16 P[16][40];  // padded: 2-way-max bank conflicts
  int bid = blockIdx.x;
  int h = bid >> 8, qb = bid & 255;
  int q0 = qb * 16;
  int lane = threadIdx.x;
  int lr = lane & 15, lgp = lane >> 4;
  const _Float16* qh = q_all + (size_t)h * T_TOK * 64;
  const _Float16* kh = k_all + (size_t)h * T_TOK * 64;
  const _Float16* vt = vT_all + (size_t)h * 64 * T_TOK;

  half8 aq0 = *(const half8*)&qh[(size_t)(q0 + lr) * 64 + lgp * 8];
  half8 aq1 = *(const half8*)&qh[(size_t)(q0 + lr) * 64 + 32 + lgp * 8];

  f32x4 acc_g[4] = {}, acc_l[4] = {};
  float m_g[4], l_g[4], m_l[4], l_l[4];
#pragma unroll
  for (int r = 0; r < 4; ++r) { m_g[r] = m_l[r] = -1e30f; l_g[r] = l_l[r] = 0.f; }

  auto chunk = [&](int key0, bool use_mask, f32x4 (&acc)[4], float (&ms)[4], float (&ls)[4]) {
    half8 b00 = *(const half8*)&kh[(size_t)(key0 + lr) * 64 + lgp * 8];
    half8 b01 = *(const half8*)&kh[(size_t)(key0 + lr) * 64 + 32 + lgp * 8];
    half8 b10 = *(const half8*)&kh[(size_t)(key0 + 16 + lr) * 64 + lgp * 8];
    half8 b11 = *(const half8*)&kh[(size_t)(key0 + 16 + lr) * 64 + 32 + lgp * 8];
    f32x4 s0 = {}, s1 = {};
    s0 = MFMA(aq0, b00, s0); s0 = MFMA(aq1, b01, s0);
    s1 = MFMA(aq0, b10, s1); s1 = MFMA(aq1, b11, s1);
    float sc[2][4];
#pragma unroll
    for (int r = 0; r < 4; ++r) { sc[0][r] = s0[r] * 0.125f; sc[1][r] = s1[r] * 0.125f; }
    if (use_mask) {
#pragma unroll
      for (int nt = 0; nt < 2; ++nt)
#pragma unroll
        for (int r = 0; r < 4; ++r) {
          int key = key0 + nt * 16 + lr, q = q0 + lgp * 4 + r;
          if (key < q - WLOC || key > q + WLOC) sc[nt][r] = -1e30f;
        }
    }
    float mx[4];
#pragma unroll
    for (int r = 0; r < 4; ++r) mx[r] = fmaxf(sc[0][r], sc[1][r]);
#pragma unroll
    for (int off = 1; off < 16; off <<= 1)
#pragma unroll
      for (int r = 0; r < 4; ++r) mx[r] = fmaxf(mx[r], __shfl_xor(mx[r], off));
    float al[4];
#pragma unroll
    for (int r = 0; r < 4; ++r) {
      float mn = fmaxf(ms[r], mx[r]);
      al[r] = __expf(ms[r] - mn);
      ms[r] = mn;
    }
    float p0[4], p1[4], rs[4];
#pragma unroll
    for (int r = 0; r < 4; ++r) {
      p0[r] = __expf(sc[0][r] - ms[r]);
      p1[r] = __expf(sc[1][r] - ms[r]);
      rs[r] = p0[r] + p1[r];
    }
#pragma unroll
    for (int off = 1; off < 16; off <<= 1)
#pragma unroll
      for (int r = 0; r < 4; ++r) rs[r] += __shfl_xor(rs[r], off);
#pragma unroll
    for (int r = 0; r < 4; ++r) ls[r] = ls[r] * al[r] + rs[r];
#pragma unroll
    for (int dt = 0; dt < 4; ++dt)
#pragma unroll
      for (int r = 0; r < 4; ++r) acc[dt][r] *= al[r];
#pragma unroll
    for (int r = 0; r < 4; ++r) {
      P[lgp * 4 + r][lr] = (_Float16)p0[r];
      P[lgp * 4 + r][16 + lr] = (_Float16)p1[r];
    }
    __syncthreads();
    half8 pa = *(half8*)&P[lr][lgp * 8];
#pragma unroll
    for (int dt = 0; dt < 4; ++dt) {
      half8 bv = *(const half8*)&vt[(size_t)(dt * 16 + lr) * T_TOK + key0 + lgp * 8];
      acc[dt] = MFMA(pa, bv, acc[dt]);
    }
    __syncthreads();
  };

  // global pass: first 64 keys
  chunk(0, false, acc_g, m_g, l_g);
  chunk(32, false, acc_g, m_g, l_g);

  // local pass: banded window
  int lo = q0 - WLOC; if (lo < 0) lo = 0;
  int hi = q0 + 15 + WLOC + 1; if (hi > T_TOK) hi = T_TOK;
  for (int kc = lo >> 5; kc < ((hi + 31) >> 5); ++kc)
    chunk(kc * 32, true, acc_l, m_l, l_l);

#pragma unroll
  for (int r = 0; r < 4; ++r) {
    int q = q0 + lgp * 4 + r;
    float g = gate[q];
#pragma unroll
    for (int dt = 0; dt < 4; ++dt) {
      float o = (1.f - g) * (acc_l[dt][r] / l_l[r]) + g * (acc_g[dt][r] / l_g[r]);
      attn_h[(size_t)q * DMODEL + h * 64 + dt * 16 + lr] = (_Float16)o;
    }
  }
}

extern "C" void kernel_launch(void* const* d_in, const int* in_sizes, int n_in,
                              void* d_out, int out_size, void* d_ws, size_t ws_size,
                              hipStream_t stream) {
  const float* hs   = (const float*)d_in[0];
  const float* Wqkv = (const float*)d_in[1];
  const float* bqkv = (const float*)d_in[2];
  const float* Wout = (const float*)d_in[3];
  const float* bout = (const float*)d_in[4];
  const float* Wg   = (const float*)d_in[5];
  const float* bg   = (const float*)d_in[6];
  float* out = (float*)d_out;

  char* ws = (char*)d_ws;
  _Float16* hidden_h = (_Float16*)(ws);               // 8 MB   [4096][1024]
  _Float16* Wqkv_t   = (_Float16*)(ws + 8388608);     // 6 MB   [3072][1024]
  _Float16* Wout_t   = (_Float16*)(ws + 14680064);    // 2 MB   [1024][1024]
  _Float16* q_h      = (_Float16*)(ws + 16777216);    // 8 MB   [16][4096][64]
  _Float16* k_h      = (_Float16*)(ws + 25165824);    // 8 MB   [16][4096][64]
  _Float16* vT_h     = (_Float16*)(ws + 33554432);    // 8 MB   [16][64][4096]
  float*    gate     = (float*)(ws + 41943040);       // 16 KB  [4096]
  _Float16* attn_h   = hidden_h;  // reuse: hidden_h dead after QKV GEMM

  k_cast<<<2048, 256, 0, stream>>>(hs, hidden_h);                      // 4096*1024/8/256
  k_gate<<<1024, 256, 0, stream>>>(hs, Wg, bg, gate);
  k_transpose_cast<<<dim3(48, 16), 256, 0, stream>>>(Wqkv, Wqkv_t, 1024, 3072);
  k_transpose_cast<<<dim3(16, 16), 256, 0, stream>>>(Wout, Wout_t, 1024, 1024);
  k_gemm<0><<<dim3(24, 32), 256, 0, stream>>>(hidden_h, Wqkv_t, bqkv, nullptr,
                                              q_h, k_h, vT_h, 4096, 3072, 1024);
  k_attn<<<4096, 64, 0, stream>>>(q_h, k_h, vT_h, gate, attn_h);
  k_gemm<1><<<dim3(8, 32), 256, 0, stream>>>(attn_h, Wout_t, bout, out,
                                             nullptr, nullptr, nullptr, 4096, 1024, 1024);
}

// Round 5
// 215.104 us; speedup vs baseline: 1.3508x; 1.3508x over previous
//
#include <hip/hip_runtime.h>

typedef _Float16 half8 __attribute__((ext_vector_type(8)));
typedef _Float16 half4_t __attribute__((ext_vector_type(4)));
typedef float f32x4 __attribute__((ext_vector_type(4)));

#define MFMA(a, b, c) __builtin_amdgcn_mfma_f32_16x16x32_f16(a, b, c, 0, 0, 0)

constexpr int T_TOK = 4096;
constexpr int DMODEL = 1024;
constexpr int WLOC = 256;

typedef const __attribute__((address_space(1))) uint32_t* gptr_t;
typedef __attribute__((address_space(3))) uint32_t* lptr_t;
static __device__ __forceinline__ void gl16(const void* g, void* l) {
  __builtin_amdgcn_global_load_lds((gptr_t)g, (lptr_t)l, 16, 0, 0);
}

// ---------- cast f32 -> f16 ----------
__global__ __launch_bounds__(256) void k_cast(const float* __restrict__ in,
                                              _Float16* __restrict__ out) {
  int i = (blockIdx.x * 256 + threadIdx.x) * 8;
  f32x4 a = *(const f32x4*)(in + i);
  f32x4 b = *(const f32x4*)(in + i + 4);
  half8 h;
  h[0] = (_Float16)a[0]; h[1] = (_Float16)a[1]; h[2] = (_Float16)a[2]; h[3] = (_Float16)a[3];
  h[4] = (_Float16)b[0]; h[5] = (_Float16)b[1]; h[6] = (_Float16)b[2]; h[7] = (_Float16)b[3];
  *(half8*)(out + i) = h;
}

// ---------- transpose + cast: f32 [R][C] -> f16 [C][R] ----------
__global__ __launch_bounds__(256) void k_transpose_cast(const float* __restrict__ in,
                                                        _Float16* __restrict__ out,
                                                        int R, int C) {
  __shared__ float tile[64][65];
  int r0 = blockIdx.y * 64, c0 = blockIdx.x * 64;
  int tr = threadIdx.x >> 4;
  int tc = (threadIdx.x & 15) * 4;
#pragma unroll
  for (int p = 0; p < 4; ++p) {
    int r = p * 16 + tr;
    f32x4 v = *(const f32x4*)&in[(size_t)(r0 + r) * C + c0 + tc];
    tile[r][tc + 0] = v[0]; tile[r][tc + 1] = v[1];
    tile[r][tc + 2] = v[2]; tile[r][tc + 3] = v[3];
  }
  __syncthreads();
#pragma unroll
  for (int p = 0; p < 4; ++p) {
    int c = p * 16 + tr;
    half4_t h;
    h[0] = (_Float16)tile[tc + 0][c];
    h[1] = (_Float16)tile[tc + 1][c];
    h[2] = (_Float16)tile[tc + 2][c];
    h[3] = (_Float16)tile[tc + 3][c];
    *(half4_t*)&out[(size_t)(c0 + c) * R + r0 + tc] = h;
  }
}

// ---------- gate ----------
__global__ __launch_bounds__(256) void k_gate(const float* __restrict__ hs,
                                              const float* __restrict__ Wg,
                                              const float* __restrict__ bg,
                                              float* __restrict__ gate) {
  int t = blockIdx.x * 4 + (threadIdx.x >> 6);
  int lane = threadIdx.x & 63;
  float s = 0.f;
#pragma unroll
  for (int i = 0; i < 16; ++i)
    s += hs[(size_t)t * DMODEL + lane + i * 64] * Wg[lane + i * 64];
#pragma unroll
  for (int off = 32; off; off >>= 1) s += __shfl_xor(s, off);
  if (lane == 0) gate[t] = 1.f / (1.f + __expf(-(s + bg[0])));
}

// ---------- f16 MFMA GEMM, m97 structure: global_load_lds(16B) -> linear LDS ----------
template <int MODE>
__global__ __launch_bounds__(256) void k_gemm(const _Float16* __restrict__ A,
                                              const _Float16* __restrict__ Bt,
                                              const float* __restrict__ bias,
                                              float* __restrict__ Cout,
                                              _Float16* __restrict__ qh,
                                              _Float16* __restrict__ kh,
                                              _Float16* __restrict__ vt,
                                              int M, int N, int K) {
  __shared__ __align__(16) _Float16 As[128][32];   // linear: LDS off = tid*16B
  __shared__ __align__(16) _Float16 Bs[128][32];
  int tid = threadIdx.x;
  int lane = tid & 63, wave = tid >> 6;
  int wm = wave >> 1, wn = wave & 1;
  int m0 = blockIdx.y * 128, n0 = blockIdx.x * 128;
  int lr = lane & 15, lk = (lane >> 4) * 8;
  int sr = tid >> 2, sc = (tid & 3) * 8;
  f32x4 acc[4][4] = {};

  for (int kt = 0; kt < K; kt += 32) {
    __syncthreads();
    gl16(&A[(size_t)(m0 + sr) * K + kt + sc],       &As[sr][sc]);
    gl16(&A[(size_t)(m0 + sr + 64) * K + kt + sc],  &As[sr + 64][sc]);
    gl16(&Bt[(size_t)(n0 + sr) * K + kt + sc],      &Bs[sr][sc]);
    gl16(&Bt[(size_t)(n0 + sr + 64) * K + kt + sc], &Bs[sr + 64][sc]);
    __syncthreads();
    half8 af[4], bf[4];
#pragma unroll
    for (int i = 0; i < 4; ++i) af[i] = *(half8*)&As[wm * 64 + i * 16 + lr][lk];
#pragma unroll
    for (int i = 0; i < 4; ++i) bf[i] = *(half8*)&Bs[wn * 64 + i * 16 + lr][lk];
#pragma unroll
    for (int i = 0; i < 4; ++i)
#pragma unroll
      for (int j = 0; j < 4; ++j)
        acc[i][j] = MFMA(af[i], bf[j], acc[i][j]);
  }

  int lg2 = lane >> 4;
#pragma unroll
  for (int j = 0; j < 4; ++j) {
    int n = n0 + wn * 64 + j * 16 + lr;
    float b = bias[n];
#pragma unroll
    for (int i = 0; i < 4; ++i) {
#pragma unroll
      for (int r = 0; r < 4; ++r) {
        int m = m0 + wm * 64 + i * 16 + lg2 * 4 + r;
        float v = acc[i][j][r] + b;
        if (MODE == 1) {
          Cout[(size_t)m * N + n] = v;
        } else {
          int hh = (n >> 6) & 15, d = n & 63;
          if (n < 1024)      qh[((size_t)hh * T_TOK + m) * 64 + d] = (_Float16)v;
          else if (n < 2048) kh[((size_t)hh * T_TOK + m) * 64 + d] = (_Float16)v;
          else               vt[((size_t)hh * 64 + d) * T_TOK + m] = (_Float16)v;
        }
      }
    }
  }
}

// ---------- fused attention: 4 waves/block, 64 queries, LDS-staged 64-key chunks ----------
__global__ __launch_bounds__(256) void k_attn(const _Float16* __restrict__ q_all,
                                              const _Float16* __restrict__ k_all,
                                              const _Float16* __restrict__ vT_all,
                                              const float* __restrict__ gate,
                                              _Float16* __restrict__ attn_h) {
  __shared__ __align__(16) _Float16 Ks[64][72];   // [key][d]
  __shared__ __align__(16) _Float16 Vs[64][72];   // [d][key]
  __shared__ __align__(16) _Float16 P[4][16][80]; // per-wave P tile

  int n = blockIdx.x;
  int o = (n & 7) * 128 + (n >> 3);   // bijective XCD swizzle (1024 % 8 == 0)
  int h = o >> 6, qb = o & 63;
  int q0 = qb * 64;
  int tid = threadIdx.x;
  int lane = tid & 63, w = tid >> 6;
  int lr = lane & 15, lgp = lane >> 4;

  const _Float16* qh = q_all + (size_t)h * T_TOK * 64;
  const _Float16* kh = k_all + (size_t)h * T_TOK * 64;
  const _Float16* vt = vT_all + (size_t)h * 64 * T_TOK;

  int qrow = q0 + w * 16 + lr;
  half8 aq0 = *(const half8*)&qh[(size_t)qrow * 64 + lgp * 8];
  half8 aq1 = *(const half8*)&qh[(size_t)qrow * 64 + 32 + lgp * 8];

  int r8 = tid >> 3, c8 = (tid & 7) * 8;

  f32x4 acc_g[4] = {}, acc_l[4] = {};
  float m_g[4], l_g[4], m_l[4], l_l[4];
#pragma unroll
  for (int r = 0; r < 4; ++r) { m_g[r] = m_l[r] = -1e30f; l_g[r] = l_l[r] = 0.f; }

  auto stage = [&](int key0) {
    half8 k0 = *(const half8*)&kh[(size_t)(key0 + r8) * 64 + c8];
    half8 k1 = *(const half8*)&kh[(size_t)(key0 + r8 + 32) * 64 + c8];
    half8 v0 = *(const half8*)&vt[(size_t)r8 * T_TOK + key0 + c8];
    half8 v1 = *(const half8*)&vt[(size_t)(r8 + 32) * T_TOK + key0 + c8];
    *(half8*)&Ks[r8][c8] = k0;
    *(half8*)&Ks[r8 + 32][c8] = k1;
    *(half8*)&Vs[r8][c8] = v0;
    *(half8*)&Vs[r8 + 32][c8] = v1;
  };

  auto compute = [&](int key0, bool use_mask, f32x4 (&acc)[4], float (&ms)[4], float (&ls)[4]) {
    f32x4 s[4] = {};
#pragma unroll
    for (int g = 0; g < 4; ++g) {
      half8 b0 = *(half8*)&Ks[g * 16 + lr][lgp * 8];
      half8 b1 = *(half8*)&Ks[g * 16 + lr][32 + lgp * 8];
      s[g] = MFMA(aq0, b0, s[g]);
      s[g] = MFMA(aq1, b1, s[g]);
    }
    float sc[4][4];
#pragma unroll
    for (int g = 0; g < 4; ++g)
#pragma unroll
      for (int r = 0; r < 4; ++r) sc[g][r] = s[g][r] * 0.125f;
    if (use_mask) {
#pragma unroll
      for (int g = 0; g < 4; ++g)
#pragma unroll
        for (int r = 0; r < 4; ++r) {
          int key = key0 + g * 16 + lr, q = q0 + w * 16 + lgp * 4 + r;
          if (key < q - WLOC || key > q + WLOC) sc[g][r] = -1e30f;
        }
    }
    float mx[4];
#pragma unroll
    for (int r = 0; r < 4; ++r)
      mx[r] = fmaxf(fmaxf(sc[0][r], sc[1][r]), fmaxf(sc[2][r], sc[3][r]));
#pragma unroll
    for (int off = 1; off < 16; off <<= 1)
#pragma unroll
      for (int r = 0; r < 4; ++r) mx[r] = fmaxf(mx[r], __shfl_xor(mx[r], off));
    float al[4];
#pragma unroll
    for (int r = 0; r < 4; ++r) {
      float mn = fmaxf(ms[r], mx[r]);
      al[r] = __expf(ms[r] - mn);
      ms[r] = mn;
    }
    float pv[4][4], rs[4] = {0.f, 0.f, 0.f, 0.f};
#pragma unroll
    for (int g = 0; g < 4; ++g)
#pragma unroll
      for (int r = 0; r < 4; ++r) {
        float x = sc[g][r];
        float p = (x > -9e29f) ? __expf(x - ms[r]) : 0.f;
        pv[g][r] = p;
        rs[r] += p;
      }
#pragma unroll
    for (int off = 1; off < 16; off <<= 1)
#pragma unroll
      for (int r = 0; r < 4; ++r) rs[r] += __shfl_xor(rs[r], off);
#pragma unroll
    for (int r = 0; r < 4; ++r) ls[r] = ls[r] * al[r] + rs[r];
#pragma unroll
    for (int dt = 0; dt < 4; ++dt)
#pragma unroll
      for (int r = 0; r < 4; ++r) acc[dt][r] *= al[r];
#pragma unroll
    for (int g = 0; g < 4; ++g)
#pragma unroll
      for (int r = 0; r < 4; ++r) P[w][lgp * 4 + r][g * 16 + lr] = (_Float16)pv[g][r];
    half8 pa0 = *(half8*)&P[w][lr][lgp * 8];
    half8 pa1 = *(half8*)&P[w][lr][32 + lgp * 8];
#pragma unroll
    for (int dt = 0; dt < 4; ++dt) {
      half8 bv0 = *(half8*)&Vs[dt * 16 + lr][lgp * 8];
      half8 bv1 = *(half8*)&Vs[dt * 16 + lr][32 + lgp * 8];
      acc[dt] = MFMA(pa0, bv0, acc[dt]);
      acc[dt] = MFMA(pa1, bv1, acc[dt]);
    }
  };

  stage(0);
  __syncthreads();
  compute(0, false, acc_g, m_g, l_g);

  int lo = q0 - WLOC; if (lo < 0) lo = 0;
  int hi = q0 + 63 + WLOC + 1; if (hi > T_TOK) hi = T_TOK;
  for (int key0 = lo; key0 < hi; key0 += 64) {
    __syncthreads();
    stage(key0);
    __syncthreads();
    compute(key0, true, acc_l, m_l, l_l);
  }

#pragma unroll
  for (int r = 0; r < 4; ++r) {
    int q = q0 + w * 16 + lgp * 4 + r;
    float g = gate[q];
#pragma unroll
    for (int dt = 0; dt < 4; ++dt) {
      float o2 = (1.f - g) * (acc_l[dt][r] / l_l[r]) + g * (acc_g[dt][r] / l_g[r]);
      attn_h[(size_t)q * DMODEL + h * 64 + dt * 16 + lr] = (_Float16)o2;
    }
  }
}

extern "C" void kernel_launch(void* const* d_in, const int* in_sizes, int n_in,
                              void* d_out, int out_size, void* d_ws, size_t ws_size,
                              hipStream_t stream) {
  const float* hs   = (const float*)d_in[0];
  const float* Wqkv = (const float*)d_in[1];
  const float* bqkv = (const float*)d_in[2];
  const float* Wout = (const float*)d_in[3];
  const float* bout = (const float*)d_in[4];
  const float* Wg   = (const float*)d_in[5];
  const float* bg   = (const float*)d_in[6];
  float* out = (float*)d_out;

  char* ws = (char*)d_ws;
  _Float16* hidden_h = (_Float16*)(ws);               // 8 MB
  _Float16* Wqkv_t   = (_Float16*)(ws + 8388608);     // 6 MB
  _Float16* Wout_t   = (_Float16*)(ws + 14680064);    // 2 MB
  _Float16* q_h      = (_Float16*)(ws + 16777216);    // 8 MB
  _Float16* k_h      = (_Float16*)(ws + 25165824);    // 8 MB
  _Float16* vT_h     = (_Float16*)(ws + 33554432);    // 8 MB
  float*    gate     = (float*)(ws + 41943040);       // 16 KB
  _Float16* attn_h   = hidden_h;  // reuse: hidden_h dead after QKV GEMM

  k_cast<<<2048, 256, 0, stream>>>(hs, hidden_h);
  k_gate<<<1024, 256, 0, stream>>>(hs, Wg, bg, gate);
  k_transpose_cast<<<dim3(48, 16), 256, 0, stream>>>(Wqkv, Wqkv_t, 1024, 3072);
  k_transpose_cast<<<dim3(16, 16), 256, 0, stream>>>(Wout, Wout_t, 1024, 1024);
  k_gemm<0><<<dim3(24, 32), 256, 0, stream>>>(hidden_h, Wqkv_t, bqkv, nullptr,
                                              q_h, k_h, vT_h, 4096, 3072, 1024);
  k_attn<<<1024, 256, 0, stream>>>(q_h, k_h, vT_h, gate, attn_h);
  k_gemm<1><<<dim3(8, 32), 256, 0, stream>>>(attn_h, Wout_t, bout, out,
                                             nullptr, nullptr, nullptr, 4096, 1024, 1024);
}

// Round 6
// 200.067 us; speedup vs baseline: 1.4523x; 1.0752x over previous
//
#include <hip/hip_runtime.h>

typedef _Float16 half8 __attribute__((ext_vector_type(8)));
typedef _Float16 half4_t __attribute__((ext_vector_type(4)));
typedef float f32x4 __attribute__((ext_vector_type(4)));

#define MFMA(a, b, c) __builtin_amdgcn_mfma_f32_16x16x32_f16(a, b, c, 0, 0, 0)

constexpr int T_TOK = 4096;
constexpr int DMODEL = 1024;
constexpr int WLOC = 256;

typedef const __attribute__((address_space(1))) uint32_t* gptr_t;
typedef __attribute__((address_space(3))) uint32_t* lptr_t;
static __device__ __forceinline__ void gl16(const void* g, void* l) {
  __builtin_amdgcn_global_load_lds((gptr_t)g, (lptr_t)l, 16, 0, 0);
}

// ---------- cast f32 -> f16 ----------
__global__ __launch_bounds__(256) void k_cast(const float* __restrict__ in,
                                              _Float16* __restrict__ out) {
  int i = (blockIdx.x * 256 + threadIdx.x) * 8;
  f32x4 a = *(const f32x4*)(in + i);
  f32x4 b = *(const f32x4*)(in + i + 4);
  half8 h;
  h[0] = (_Float16)a[0]; h[1] = (_Float16)a[1]; h[2] = (_Float16)a[2]; h[3] = (_Float16)a[3];
  h[4] = (_Float16)b[0]; h[5] = (_Float16)b[1]; h[6] = (_Float16)b[2]; h[7] = (_Float16)b[3];
  *(half8*)(out + i) = h;
}

// ---------- transpose + cast: f32 [R][C] -> f16 [C][R] ----------
__global__ __launch_bounds__(256) void k_transpose_cast(const float* __restrict__ in,
                                                        _Float16* __restrict__ out,
                                                        int R, int C) {
  __shared__ float tile[64][65];
  int r0 = blockIdx.y * 64, c0 = blockIdx.x * 64;
  int tr = threadIdx.x >> 4;
  int tc = (threadIdx.x & 15) * 4;
#pragma unroll
  for (int p = 0; p < 4; ++p) {
    int r = p * 16 + tr;
    f32x4 v = *(const f32x4*)&in[(size_t)(r0 + r) * C + c0 + tc];
    tile[r][tc + 0] = v[0]; tile[r][tc + 1] = v[1];
    tile[r][tc + 2] = v[2]; tile[r][tc + 3] = v[3];
  }
  __syncthreads();
#pragma unroll
  for (int p = 0; p < 4; ++p) {
    int c = p * 16 + tr;
    half4_t h;
    h[0] = (_Float16)tile[tc + 0][c];
    h[1] = (_Float16)tile[tc + 1][c];
    h[2] = (_Float16)tile[tc + 2][c];
    h[3] = (_Float16)tile[tc + 3][c];
    *(half4_t*)&out[(size_t)(c0 + c) * R + r0 + tc] = h;
  }
}

// ---------- gate ----------
__global__ __launch_bounds__(256) void k_gate(const float* __restrict__ hs,
                                              const float* __restrict__ Wg,
                                              const float* __restrict__ bg,
                                              float* __restrict__ gate) {
  int t = blockIdx.x * 4 + (threadIdx.x >> 6);
  int lane = threadIdx.x & 63;
  float s = 0.f;
#pragma unroll
  for (int i = 0; i < 16; ++i)
    s += hs[(size_t)t * DMODEL + lane + i * 64] * Wg[lane + i * 64];
#pragma unroll
  for (int off = 32; off; off >>= 1) s += __shfl_xor(s, off);
  if (lane == 0) gate[t] = 1.f / (1.f + __expf(-(s + bg[0])));
}

// ---------- f16 MFMA GEMM, m97 structure (unchanged this round) ----------
template <int MODE>
__global__ __launch_bounds__(256) void k_gemm(const _Float16* __restrict__ A,
                                              const _Float16* __restrict__ Bt,
                                              const float* __restrict__ bias,
                                              float* __restrict__ Cout,
                                              _Float16* __restrict__ qh,
                                              _Float16* __restrict__ kh,
                                              _Float16* __restrict__ vt,
                                              int M, int N, int K) {
  __shared__ __align__(16) _Float16 As[128][32];
  __shared__ __align__(16) _Float16 Bs[128][32];
  int tid = threadIdx.x;
  int lane = tid & 63, wave = tid >> 6;
  int wm = wave >> 1, wn = wave & 1;
  int m0 = blockIdx.y * 128, n0 = blockIdx.x * 128;
  int lr = lane & 15, lk = (lane >> 4) * 8;
  int sr = tid >> 2, sc = (tid & 3) * 8;
  f32x4 acc[4][4] = {};

  for (int kt = 0; kt < K; kt += 32) {
    __syncthreads();
    gl16(&A[(size_t)(m0 + sr) * K + kt + sc],       &As[sr][sc]);
    gl16(&A[(size_t)(m0 + sr + 64) * K + kt + sc],  &As[sr + 64][sc]);
    gl16(&Bt[(size_t)(n0 + sr) * K + kt + sc],      &Bs[sr][sc]);
    gl16(&Bt[(size_t)(n0 + sr + 64) * K + kt + sc], &Bs[sr + 64][sc]);
    __syncthreads();
    half8 af[4], bf[4];
#pragma unroll
    for (int i = 0; i < 4; ++i) af[i] = *(half8*)&As[wm * 64 + i * 16 + lr][lk];
#pragma unroll
    for (int i = 0; i < 4; ++i) bf[i] = *(half8*)&Bs[wn * 64 + i * 16 + lr][lk];
#pragma unroll
    for (int i = 0; i < 4; ++i)
#pragma unroll
      for (int j = 0; j < 4; ++j)
        acc[i][j] = MFMA(af[i], bf[j], acc[i][j]);
  }

  int lg2 = lane >> 4;
#pragma unroll
  for (int j = 0; j < 4; ++j) {
    int n = n0 + wn * 64 + j * 16 + lr;
    float b = bias[n];
#pragma unroll
    for (int i = 0; i < 4; ++i) {
#pragma unroll
      for (int r = 0; r < 4; ++r) {
        int m = m0 + wm * 64 + i * 16 + lg2 * 4 + r;
        float v = acc[i][j][r] + b;
        if (MODE == 1) {
          Cout[(size_t)m * N + n] = v;
        } else {
          int hh = (n >> 6) & 15, d = n & 63;
          if (n < 1024)      qh[((size_t)hh * T_TOK + m) * 64 + d] = (_Float16)v;
          else if (n < 2048) kh[((size_t)hh * T_TOK + m) * 64 + d] = (_Float16)v;
          else               vt[((size_t)hh * 64 + d) * T_TOK + m] = (_Float16)v;
        }
      }
    }
  }
}

// ---------- fused attention v3: swapped QK^T, lane-local softmax, T14 async-stage ----------
// 4 waves/block, 64 q/block. S^T layout: lane (lr,lgp) holds q=lr, keys g*16+lgp*4+r.
__global__ __launch_bounds__(256) void k_attn(const _Float16* __restrict__ q_all,
                                              const _Float16* __restrict__ k_all,
                                              const _Float16* __restrict__ vT_all,
                                              const float* __restrict__ gate,
                                              _Float16* __restrict__ attn_h) {
  __shared__ __align__(16) _Float16 Ks[64][72];   // [key][d], 144B rows: slot=(lr+lgp)%8 uniform
  __shared__ __align__(16) _Float16 Vs[64][72];   // [d][key]
  __shared__ __align__(16) _Float16 P[4][16][72]; // per-wave P, b64 writes / b128 reads

  int n = blockIdx.x;
  int o = (n & 7) * 128 + (n >> 3);   // bijective XCD swizzle (1024 % 8 == 0)
  int h = o >> 6, qb = o & 63;
  int q0 = qb * 64;
  int tid = threadIdx.x;
  int lane = tid & 63, w = tid >> 6;
  int lr = lane & 15, lgp = lane >> 4;

  const _Float16* qh = q_all + (size_t)h * T_TOK * 64;
  const _Float16* kh = k_all + (size_t)h * T_TOK * 64;
  const _Float16* vt = vT_all + (size_t)h * 64 * T_TOK;

  // Q fragment (B-operand), pre-scaled by 1/sqrt(64) = 0.125 (exact in f16)
  half8 aq0 = *(const half8*)&qh[(size_t)(q0 + w * 16 + lr) * 64 + lgp * 8];
  half8 aq1 = *(const half8*)&qh[(size_t)(q0 + w * 16 + lr) * 64 + 32 + lgp * 8];
#pragma unroll
  for (int j = 0; j < 8; ++j) { aq0[j] = aq0[j] * (_Float16)0.125f; aq1[j] = aq1[j] * (_Float16)0.125f; }

  int r8 = tid >> 3, c8 = (tid & 7) * 8;
  half8 kr0, kr1, vr0, vr1;   // T14 staging registers

  auto ldregs = [&](int key0) {
    kr0 = *(const half8*)&kh[(size_t)(key0 + r8) * 64 + c8];
    kr1 = *(const half8*)&kh[(size_t)(key0 + r8 + 32) * 64 + c8];
    vr0 = *(const half8*)&vt[(size_t)r8 * T_TOK + key0 + c8];
    vr1 = *(const half8*)&vt[(size_t)(r8 + 32) * T_TOK + key0 + c8];
  };
  auto dswrite = [&]() {
    *(half8*)&Ks[r8][c8]      = kr0;
    *(half8*)&Ks[r8 + 32][c8] = kr1;
    *(half8*)&Vs[r8][c8]      = vr0;
    *(half8*)&Vs[r8 + 32][c8] = vr1;
  };

  f32x4 acc_g[4] = {}, acc_l[4] = {};
  float m_g = -1e30f, l_g = 0.f, m_l = -1e30f, l_l = 0.f;

  auto compute = [&](int key0, bool use_mask, f32x4 (&acc)[4], float& ms, float& ls) {
    f32x4 s[4] = {};
#pragma unroll
    for (int g = 0; g < 4; ++g) {
      half8 b0 = *(half8*)&Ks[g * 16 + lr][lgp * 8];
      half8 b1 = *(half8*)&Ks[g * 16 + lr][32 + lgp * 8];
      s[g] = MFMA(b0, aq0, s[g]);   // A=K rows, B=Q cols -> S^T (pre-scaled)
      s[g] = MFMA(b1, aq1, s[g]);
    }
    if (use_mask) {
      int moff = key0 + lgp * 4 - (q0 + w * 16 + lr) + WLOC;  // key - q + 256
#pragma unroll
      for (int g = 0; g < 4; ++g)
#pragma unroll
        for (int r = 0; r < 4; ++r) {
          unsigned u = (unsigned)(moff + g * 16 + r);
          if (u > 2u * WLOC) s[g][r] = -1e30f;
        }
    }
    // lane-local max over this lane's 16 keys, then reduce over the 4 lgp groups
    float mloc = -1e30f;
#pragma unroll
    for (int g = 0; g < 4; ++g)
#pragma unroll
      for (int r = 0; r < 4; ++r) mloc = fmaxf(mloc, s[g][r]);
    mloc = fmaxf(mloc, __shfl_xor(mloc, 16));
    mloc = fmaxf(mloc, __shfl_xor(mloc, 32));
    if (__any(mloc > ms)) {          // T13: skip rescale when running max unchanged
      float mn = fmaxf(ms, mloc);
      float al = __expf(ms - mn);
      ms = mn;
      float alr[4];
#pragma unroll
      for (int r = 0; r < 4; ++r) alr[r] = __shfl(al, lgp * 4 + r);
#pragma unroll
      for (int dt = 0; dt < 4; ++dt)
#pragma unroll
        for (int r = 0; r < 4; ++r) acc[dt][r] *= alr[r];
      ls *= al;
    }
    float rsum = 0.f;
#pragma unroll
    for (int g = 0; g < 4; ++g)
#pragma unroll
      for (int r = 0; r < 4; ++r) {
        float p = __expf(s[g][r] - ms);  // masked: exp(-1e30-ms) underflows to 0
        s[g][r] = p;
        rsum += p;
      }
    rsum += __shfl_xor(rsum, 16);
    rsum += __shfl_xor(rsum, 32);
    ls += rsum;
    // pack 4 consecutive keys -> one b64 write; read back as A-fragment rows
#pragma unroll
    for (int g = 0; g < 4; ++g) {
      half4_t q4;
      q4[0] = (_Float16)s[g][0]; q4[1] = (_Float16)s[g][1];
      q4[2] = (_Float16)s[g][2]; q4[3] = (_Float16)s[g][3];
      *(half4_t*)&P[w][lr][g * 16 + lgp * 4] = q4;
    }
    half8 pa0 = *(half8*)&P[w][lr][lgp * 8];        // same-wave RAW: in-order DS pipe
    half8 pa1 = *(half8*)&P[w][lr][32 + lgp * 8];
#pragma unroll
    for (int dt = 0; dt < 4; ++dt) {
      half8 bv0 = *(half8*)&Vs[dt * 16 + lr][lgp * 8];
      half8 bv1 = *(half8*)&Vs[dt * 16 + lr][32 + lgp * 8];
      acc[dt] = MFMA(pa0, bv0, acc[dt]);
      acc[dt] = MFMA(pa1, bv1, acc[dt]);
    }
  };

  // ---- global pass (keys 0..63), with first local chunk prefetched under it ----
  ldregs(0);
  dswrite();
  __syncthreads();
  int lo = q0 - WLOC; if (lo < 0) lo = 0;
  int hi = q0 + 63 + WLOC + 1; if (hi > T_TOK) hi = T_TOK;
  ldregs(lo);                       // overlap with global-pass compute
  compute(0, false, acc_g, m_g, l_g);
  __syncthreads();
  dswrite();
  __syncthreads();

  // ---- local pass ----
  for (int key0 = lo; key0 < hi; key0 += 64) {
    int nxt = key0 + 64;
    bool have_nxt = nxt < hi;
    if (have_nxt) ldregs(nxt);      // T14: issue loads before compute
    bool use_mask = (key0 < q0 - 192) || (key0 > q0 + 192);
    compute(key0, use_mask, acc_l, m_l, l_l);
    __syncthreads();
    if (have_nxt) { dswrite(); __syncthreads(); }
  }

  // ---- epilogue: acc rows are q = q0+w*16+lgp*4+r, cols d = dt*16+lr ----
  float llr[4], lgr[4];
#pragma unroll
  for (int r = 0; r < 4; ++r) {
    llr[r] = __shfl(l_l, lgp * 4 + r);
    lgr[r] = __shfl(l_g, lgp * 4 + r);
  }
#pragma unroll
  for (int r = 0; r < 4; ++r) {
    int q = q0 + w * 16 + lgp * 4 + r;
    float g = gate[q];
#pragma unroll
    for (int dt = 0; dt < 4; ++dt) {
      float o2 = (1.f - g) * (acc_l[dt][r] / llr[r]) + g * (acc_g[dt][r] / lgr[r]);
      attn_h[(size_t)q * DMODEL + h * 64 + dt * 16 + lr] = (_Float16)o2;
    }
  }
}

extern "C" void kernel_launch(void* const* d_in, const int* in_sizes, int n_in,
                              void* d_out, int out_size, void* d_ws, size_t ws_size,
                              hipStream_t stream) {
  const float* hs   = (const float*)d_in[0];
  const float* Wqkv = (const float*)d_in[1];
  const float* bqkv = (const float*)d_in[2];
  const float* Wout = (const float*)d_in[3];
  const float* bout = (const float*)d_in[4];
  const float* Wg   = (const float*)d_in[5];
  const float* bg   = (const float*)d_in[6];
  float* out = (float*)d_out;

  char* ws = (char*)d_ws;
  _Float16* hidden_h = (_Float16*)(ws);               // 8 MB
  _Float16* Wqkv_t   = (_Float16*)(ws + 8388608);     // 6 MB
  _Float16* Wout_t   = (_Float16*)(ws + 14680064);    // 2 MB
  _Float16* q_h      = (_Float16*)(ws + 16777216);    // 8 MB
  _Float16* k_h      = (_Float16*)(ws + 25165824);    // 8 MB
  _Float16* vT_h     = (_Float16*)(ws + 33554432);    // 8 MB
  float*    gate     = (float*)(ws + 41943040);       // 16 KB
  _Float16* attn_h   = hidden_h;  // reuse: hidden_h dead after QKV GEMM

  k_cast<<<2048, 256, 0, stream>>>(hs, hidden_h);
  k_gate<<<1024, 256, 0, stream>>>(hs, Wg, bg, gate);
  k_transpose_cast<<<dim3(48, 16), 256, 0, stream>>>(Wqkv, Wqkv_t, 1024, 3072);
  k_transpose_cast<<<dim3(16, 16), 256, 0, stream>>>(Wout, Wout_t, 1024, 1024);
  k_gemm<0><<<dim3(24, 32), 256, 0, stream>>>(hidden_h, Wqkv_t, bqkv, nullptr,
                                              q_h, k_h, vT_h, 4096, 3072, 1024);
  k_attn<<<1024, 256, 0, stream>>>(q_h, k_h, vT_h, gate, attn_h);
  k_gemm<1><<<dim3(8, 32), 256, 0, stream>>>(attn_h, Wout_t, bout, out,
                                             nullptr, nullptr, nullptr, 4096, 1024, 1024);
}

// Round 8
// 185.529 us; speedup vs baseline: 1.5661x; 1.0784x over previous
//
#include <hip/hip_runtime.h>

typedef _Float16 half8 __attribute__((ext_vector_type(8)));
typedef _Float16 half4_t __attribute__((ext_vector_type(4)));
typedef float f32x4 __attribute__((ext_vector_type(4)));

#define MFMA(a, b, c) __builtin_amdgcn_mfma_f32_16x16x32_f16(a, b, c, 0, 0, 0)

constexpr int T_TOK = 4096;
constexpr int DMODEL = 1024;
constexpr int WLOC = 256;

typedef const __attribute__((address_space(1))) uint32_t* gptr_t;
typedef __attribute__((address_space(3))) uint32_t* lptr_t;
static __device__ __forceinline__ void gl16(const void* g, void* l) {
  __builtin_amdgcn_global_load_lds((gptr_t)g, (lptr_t)l, 16, 0, 0);
}

// ---------- fused cast f32->f16 + gate (one pass over hs) ----------
__global__ __launch_bounds__(256) void k_castgate(const float* __restrict__ hs,
                                                  const float* __restrict__ Wg,
                                                  const float* __restrict__ bg,
                                                  _Float16* __restrict__ out,
                                                  float* __restrict__ gate) {
  int w = threadIdx.x >> 6, lane = threadIdx.x & 63;
  int t = blockIdx.x * 4 + w;
  const float* row = hs + (size_t)t * DMODEL;
  _Float16* orow = out + (size_t)t * DMODEL;
  float s = 0.f;
#pragma unroll
  for (int i = 0; i < 4; ++i) {
    int off = lane * 4 + i * 256;
    f32x4 v = *(const f32x4*)(row + off);
    f32x4 g = *(const f32x4*)(Wg + off);
    s += v[0] * g[0] + v[1] * g[1] + v[2] * g[2] + v[3] * g[3];
    half4_t h;
    h[0] = (_Float16)v[0]; h[1] = (_Float16)v[1];
    h[2] = (_Float16)v[2]; h[3] = (_Float16)v[3];
    *(half4_t*)(orow + off) = h;
  }
#pragma unroll
  for (int off = 32; off; off >>= 1) s += __shfl_xor(s, off);
  if (lane == 0) gate[t] = 1.f / (1.f + __expf(-(s + bg[0])));
}

// ---------- transpose + cast: f32 [R][C] -> f16 [C][R] ----------
__global__ __launch_bounds__(256) void k_transpose_cast(const float* __restrict__ in,
                                                        _Float16* __restrict__ out,
                                                        int R, int C) {
  __shared__ float tile[64][65];
  int r0 = blockIdx.y * 64, c0 = blockIdx.x * 64;
  int tr = threadIdx.x >> 4;
  int tc = (threadIdx.x & 15) * 4;
#pragma unroll
  for (int p = 0; p < 4; ++p) {
    int r = p * 16 + tr;
    f32x4 v = *(const f32x4*)&in[(size_t)(r0 + r) * C + c0 + tc];
    tile[r][tc + 0] = v[0]; tile[r][tc + 1] = v[1];
    tile[r][tc + 2] = v[2]; tile[r][tc + 3] = v[3];
  }
  __syncthreads();
#pragma unroll
  for (int p = 0; p < 4; ++p) {
    int c = p * 16 + tr;
    half4_t h;
    h[0] = (_Float16)tile[tc + 0][c];
    h[1] = (_Float16)tile[tc + 1][c];
    h[2] = (_Float16)tile[tc + 2][c];
    h[3] = (_Float16)tile[tc + 3][c];
    *(half4_t*)&out[(size_t)(c0 + c) * R + r0 + tc] = h;
  }
}

// ---------- f16 MFMA GEMM: dbuf 2-phase (T3 minimum recipe) + XCD swizzle ----------
// 1-D grid, nwg % 8 == 0. bx = wg % NBX (n-dim), by = wg / NBX (m-dim).
template <int MODE, int NBX>
__global__ __launch_bounds__(256) void k_gemm(const _Float16* __restrict__ A,
                                              const _Float16* __restrict__ Bt,
                                              const float* __restrict__ bias,
                                              float* __restrict__ Cout,
                                              _Float16* __restrict__ qh,
                                              _Float16* __restrict__ kh,
                                              _Float16* __restrict__ vt,
                                              int M, int N, int K) {
  __shared__ __align__(16) _Float16 As[2][128][32];   // 2 x 8 KB, linear for gl16
  __shared__ __align__(16) _Float16 Bs[2][128][32];
  int nwg = gridDim.x;
  int cpx = nwg >> 3;
  int orig = blockIdx.x;
  int wg = (orig & 7) * cpx + (orig >> 3);   // bijective XCD swizzle (nwg%8==0)
  int bx = wg % NBX, by = wg / NBX;
  int m0 = by * 128, n0 = bx * 128;

  int tid = threadIdx.x;
  int lane = tid & 63, wave = tid >> 6;
  int wm = wave >> 1, wn = wave & 1;
  int lr = lane & 15, lk = (lane >> 4) * 8;
  int sr = tid >> 2, sc = (tid & 3) * 8;
  f32x4 acc[4][4] = {};

  auto stage = [&](int kt, int b) {
    gl16(&A[(size_t)(m0 + sr) * K + kt + sc],       &As[b][sr][sc]);
    gl16(&A[(size_t)(m0 + sr + 64) * K + kt + sc],  &As[b][sr + 64][sc]);
    gl16(&Bt[(size_t)(n0 + sr) * K + kt + sc],      &Bs[b][sr][sc]);
    gl16(&Bt[(size_t)(n0 + sr + 64) * K + kt + sc], &Bs[b][sr + 64][sc]);
  };

  stage(0, 0);
  __syncthreads();                       // prologue drain: buf0 ready
  int cur = 0;
  for (int kt = 0; kt < K; kt += 32) {
    if (kt + 32 < K) stage(kt + 32, cur ^ 1);   // issue next-tile loads FIRST
    half8 af[4], bf[4];
#pragma unroll
    for (int i = 0; i < 4; ++i) af[i] = *(half8*)&As[cur][wm * 64 + i * 16 + lr][lk];
#pragma unroll
    for (int i = 0; i < 4; ++i) bf[i] = *(half8*)&Bs[cur][wn * 64 + i * 16 + lr][lk];
#pragma unroll
    for (int i = 0; i < 4; ++i)
#pragma unroll
      for (int j = 0; j < 4; ++j)
        acc[i][j] = MFMA(af[i], bf[j], acc[i][j]);
    __syncthreads();                     // one barrier/step: drains vmcnt (next buf
    cur ^= 1;                            // ready) + guards buf reuse next iter
  }

  int lg2 = lane >> 4;
#pragma unroll
  for (int j = 0; j < 4; ++j) {
    int n = n0 + wn * 64 + j * 16 + lr;
    float b = bias[n];
#pragma unroll
    for (int i = 0; i < 4; ++i) {
#pragma unroll
      for (int r = 0; r < 4; ++r) {
        int m = m0 + wm * 64 + i * 16 + lg2 * 4 + r;
        float v = acc[i][j][r] + b;
        if (MODE == 1) {
          Cout[(size_t)m * N + n] = v;
        } else {
          int hh = (n >> 6) & 15, d = n & 63;
          if (n < 1024)      qh[((size_t)hh * T_TOK + m) * 64 + d] = (_Float16)v;
          else if (n < 2048) kh[((size_t)hh * T_TOK + m) * 64 + d] = (_Float16)v;
          else               vt[((size_t)hh * 64 + d) * T_TOK + m] = (_Float16)v;
        }
      }
    }
  }
}

// ---------- fused attention v3 (unchanged) ----------
__global__ __launch_bounds__(256) void k_attn(const _Float16* __restrict__ q_all,
                                              const _Float16* __restrict__ k_all,
                                              const _Float16* __restrict__ vT_all,
                                              const float* __restrict__ gate,
                                              _Float16* __restrict__ attn_h) {
  __shared__ __align__(16) _Float16 Ks[64][72];
  __shared__ __align__(16) _Float16 Vs[64][72];
  __shared__ __align__(16) _Float16 P[4][16][72];

  int n = blockIdx.x;
  int o = (n & 7) * 128 + (n >> 3);
  int h = o >> 6, qb = o & 63;
  int q0 = qb * 64;
  int tid = threadIdx.x;
  int lane = tid & 63, w = tid >> 6;
  int lr = lane & 15, lgp = lane >> 4;

  const _Float16* qh = q_all + (size_t)h * T_TOK * 64;
  const _Float16* kh = k_all + (size_t)h * T_TOK * 64;
  const _Float16* vt = vT_all + (size_t)h * 64 * T_TOK;

  half8 aq0 = *(const half8*)&qh[(size_t)(q0 + w * 16 + lr) * 64 + lgp * 8];
  half8 aq1 = *(const half8*)&qh[(size_t)(q0 + w * 16 + lr) * 64 + 32 + lgp * 8];
#pragma unroll
  for (int j = 0; j < 8; ++j) { aq0[j] = aq0[j] * (_Float16)0.125f; aq1[j] = aq1[j] * (_Float16)0.125f; }

  int r8 = tid >> 3, c8 = (tid & 7) * 8;
  half8 kr0, kr1, vr0, vr1;

  auto ldregs = [&](int key0) {
    kr0 = *(const half8*)&kh[(size_t)(key0 + r8) * 64 + c8];
    kr1 = *(const half8*)&kh[(size_t)(key0 + r8 + 32) * 64 + c8];
    vr0 = *(const half8*)&vt[(size_t)r8 * T_TOK + key0 + c8];
    vr1 = *(const half8*)&vt[(size_t)(r8 + 32) * T_TOK + key0 + c8];
  };
  auto dswrite = [&]() {
    *(half8*)&Ks[r8][c8]      = kr0;
    *(half8*)&Ks[r8 + 32][c8] = kr1;
    *(half8*)&Vs[r8][c8]      = vr0;
    *(half8*)&Vs[r8 + 32][c8] = vr1;
  };

  f32x4 acc_g[4] = {}, acc_l[4] = {};
  float m_g = -1e30f, l_g = 0.f, m_l = -1e30f, l_l = 0.f;

  auto compute = [&](int key0, bool use_mask, f32x4 (&acc)[4], float& ms, float& ls) {
    f32x4 s[4] = {};
#pragma unroll
    for (int g = 0; g < 4; ++g) {
      half8 b0 = *(half8*)&Ks[g * 16 + lr][lgp * 8];
      half8 b1 = *(half8*)&Ks[g * 16 + lr][32 + lgp * 8];
      s[g] = MFMA(b0, aq0, s[g]);
      s[g] = MFMA(b1, aq1, s[g]);
    }
    if (use_mask) {
      int moff = key0 + lgp * 4 - (q0 + w * 16 + lr) + WLOC;
#pragma unroll
      for (int g = 0; g < 4; ++g)
#pragma unroll
        for (int r = 0; r < 4; ++r) {
          unsigned u = (unsigned)(moff + g * 16 + r);
          if (u > 2u * WLOC) s[g][r] = -1e30f;
        }
    }
    float mloc = -1e30f;
#pragma unroll
    for (int g = 0; g < 4; ++g)
#pragma unroll
      for (int r = 0; r < 4; ++r) mloc = fmaxf(mloc, s[g][r]);
    mloc = fmaxf(mloc, __shfl_xor(mloc, 16));
    mloc = fmaxf(mloc, __shfl_xor(mloc, 32));
    if (__any(mloc > ms)) {
      float mn = fmaxf(ms, mloc);
      float al = __expf(ms - mn);
      ms = mn;
      float alr[4];
#pragma unroll
      for (int r = 0; r < 4; ++r) alr[r] = __shfl(al, lgp * 4 + r);
#pragma unroll
      for (int dt = 0; dt < 4; ++dt)
#pragma unroll
        for (int r = 0; r < 4; ++r) acc[dt][r] *= alr[r];
      ls *= al;
    }
    float rsum = 0.f;
#pragma unroll
    for (int g = 0; g < 4; ++g)
#pragma unroll
      for (int r = 0; r < 4; ++r) {
        float p = __expf(s[g][r] - ms);
        s[g][r] = p;
        rsum += p;
      }
    rsum += __shfl_xor(rsum, 16);
    rsum += __shfl_xor(rsum, 32);
    ls += rsum;
#pragma unroll
    for (int g = 0; g < 4; ++g) {
      half4_t q4;
      q4[0] = (_Float16)s[g][0]; q4[1] = (_Float16)s[g][1];
      q4[2] = (_Float16)s[g][2]; q4[3] = (_Float16)s[g][3];
      *(half4_t*)&P[w][lr][g * 16 + lgp * 4] = q4;
    }
    half8 pa0 = *(half8*)&P[w][lr][lgp * 8];
    half8 pa1 = *(half8*)&P[w][lr][32 + lgp * 8];
#pragma unroll
    for (int dt = 0; dt < 4; ++dt) {
      half8 bv0 = *(half8*)&Vs[dt * 16 + lr][lgp * 8];
      half8 bv1 = *(half8*)&Vs[dt * 16 + lr][32 + lgp * 8];
      acc[dt] = MFMA(pa0, bv0, acc[dt]);
      acc[dt] = MFMA(pa1, bv1, acc[dt]);
    }
  };

  ldregs(0);
  dswrite();
  __syncthreads();
  int lo = q0 - WLOC; if (lo < 0) lo = 0;
  int hi = q0 + 63 + WLOC + 1; if (hi > T_TOK) hi = T_TOK;
  ldregs(lo);
  compute(0, false, acc_g, m_g, l_g);
  __syncthreads();
  dswrite();
  __syncthreads();

  for (int key0 = lo; key0 < hi; key0 += 64) {
    int nxt = key0 + 64;
    bool have_nxt = nxt < hi;
    if (have_nxt) ldregs(nxt);
    bool use_mask = (key0 < q0 - 192) || (key0 > q0 + 192);
    compute(key0, use_mask, acc_l, m_l, l_l);
    __syncthreads();
    if (have_nxt) { dswrite(); __syncthreads(); }
  }

  float llr[4], lgr[4];
#pragma unroll
  for (int r = 0; r < 4; ++r) {
    llr[r] = __shfl(l_l, lgp * 4 + r);
    lgr[r] = __shfl(l_g, lgp * 4 + r);
  }
#pragma unroll
  for (int r = 0; r < 4; ++r) {
    int q = q0 + w * 16 + lgp * 4 + r;
    float g = gate[q];
#pragma unroll
    for (int dt = 0; dt < 4; ++dt) {
      float o2 = (1.f - g) * (acc_l[dt][r] / llr[r]) + g * (acc_g[dt][r] / lgr[r]);
      attn_h[(size_t)q * DMODEL + h * 64 + dt * 16 + lr] = (_Float16)o2;
    }
  }
}

extern "C" void kernel_launch(void* const* d_in, const int* in_sizes, int n_in,
                              void* d_out, int out_size, void* d_ws, size_t ws_size,
                              hipStream_t stream) {
  const float* hs   = (const float*)d_in[0];
  const float* Wqkv = (const float*)d_in[1];
  const float* bqkv = (const float*)d_in[2];
  const float* Wout = (const float*)d_in[3];
  const float* bout = (const float*)d_in[4];
  const float* Wg   = (const float*)d_in[5];
  const float* bg   = (const float*)d_in[6];
  float* out = (float*)d_out;

  char* ws = (char*)d_ws;
  _Float16* hidden_h = (_Float16*)(ws);               // 8 MB
  _Float16* Wqkv_t   = (_Float16*)(ws + 8388608);     // 6 MB
  _Float16* Wout_t   = (_Float16*)(ws + 14680064);    // 2 MB
  _Float16* q_h      = (_Float16*)(ws + 16777216);    // 8 MB
  _Float16* k_h      = (_Float16*)(ws + 25165824);    // 8 MB
  _Float16* vT_h     = (_Float16*)(ws + 33554432);    // 8 MB
  float*    gate     = (float*)(ws + 41943040);       // 16 KB
  _Float16* attn_h   = hidden_h;  // reuse: hidden_h dead after QKV GEMM

  k_castgate<<<1024, 256, 0, stream>>>(hs, Wg, bg, hidden_h, gate);
  k_transpose_cast<<<dim3(48, 16), 256, 0, stream>>>(Wqkv, Wqkv_t, 1024, 3072);
  k_transpose_cast<<<dim3(16, 16), 256, 0, stream>>>(Wout, Wout_t, 1024, 1024);
  k_gemm<0, 24><<<768, 256, 0, stream>>>(hidden_h, Wqkv_t, bqkv, nullptr,
                                         q_h, k_h, vT_h, 4096, 3072, 1024);
  k_attn<<<1024, 256, 0, stream>>>(q_h, k_h, vT_h, gate, attn_h);
  k_gemm<1, 8><<<256, 256, 0, stream>>>(attn_h, Wout_t, bout, out,
                                        nullptr, nullptr, nullptr, 4096, 1024, 1024);
}